// Round 3
// baseline (271.914 us; speedup 1.0000x reference)
//
#include <hip/hip_runtime.h>
#include <cmath>

// Problem constants (fixed instantiation): x is [B, D] float32.
constexpr int B = 256;
constexpr int D = 512;
constexpr int ROW = D + D * D + D;     // 263168 floats per output row
constexpr int G = 2048;                // persistent grid: 8 blocks/CU on 256 CUs
constexpr int CHUNKS = B * 256;        // pair region = 256 rows x 1MB = 65536 x 4KB chunks
constexpr int ITERS = CHUNKS / G;      // 32 (exact)

// Clang native vector type (accepted by __builtin_nontemporal_store).
typedef float f4 __attribute__((ext_vector_type(4)));

// Fill-mimicking writer: at iteration k the WHOLE GRID writes chunks
// [k*G, (k+1)*G) — an 8MB contiguous moving window over the output, matching
// the access shape of the 6.4 TB/s fillBuffer kernel (vs. our previous 2048
// scattered per-block streams at ~2.9 TB/s effective).
__global__ __launch_bounds__(256)
void basis_expansion_kernel(const float* __restrict__ x, float* __restrict__ out) {
    const int bid  = blockIdx.x;
    const int t    = threadIdx.x;
    const int half = t >> 7;           // chunk sub-row 0/1 (uniform per wave)
    const int col4 = t & 127;          // float4 column within a 512-float row

    const f4* x4 = reinterpret_cast<const f4*>(x);

#pragma unroll 4
    for (int k = 0; k < ITERS; ++k) {
        const int c   = k * G + bid;   // device-linear chunk index
        const int b   = c >> 8;        // 256 chunks per batch row
        const int ci  = c & 255;
        const int row = ci * 2 + half; // pair row i in [0, 512)
        // x is 512KB -> L2-resident; scalar a is a wave-broadcast load.
        const float a = x[b * D + row];
        const f4 v = x4[b * 128 + col4];
        f4 w;
        w.x = a * v.x; w.y = a * v.y; w.z = a * v.z; w.w = a * v.w;
        f4* dst = reinterpret_cast<f4*>(out + (size_t)b * ROW + D) + (row * 128 + col4);
        __builtin_nontemporal_store(w, dst);   // global_store_dwordx4 nt, coalesced
    }

    // sin + identity tail (512KB total): blocks 0..63, 4 float4s per thread.
    // q in [0, 65536): 256 f4 per batch row = 128 sin f4 + 128 ident f4.
    if (bid < 64) {
        const int s = bid * 256 + t;   // [0, 16384)
#pragma unroll
        for (int q0 = 0; q0 < 4; ++q0) {
            const int q = q0 * 16384 + s;
            const int b = q >> 8;
            const int r = q & 255;
            const f4* xr = x4 + b * 128;
            float* orow = out + (size_t)b * ROW;
            if (r < 128) {
                const f4 vv = xr[r];
                f4 sres;
                sres.x = sinf(vv.x); sres.y = sinf(vv.y);
                sres.z = sinf(vv.z); sres.w = sinf(vv.w);
                __builtin_nontemporal_store(sres, reinterpret_cast<f4*>(orow) + r);
            } else {
                const f4 vv = xr[r - 128];
                __builtin_nontemporal_store(vv,
                    reinterpret_cast<f4*>(orow + D + D * D) + (r - 128));
            }
        }
    }
}

extern "C" void kernel_launch(void* const* d_in, const int* in_sizes, int n_in,
                              void* d_out, int out_size, void* d_ws, size_t ws_size,
                              hipStream_t stream) {
    const float* x = (const float*)d_in[0];
    float* out = (float*)d_out;
    dim3 grid(G);
    dim3 block(256);
    basis_expansion_kernel<<<grid, block, 0, stream>>>(x, out);
}

// Round 5
// 255.696 us; speedup vs baseline: 1.0634x; 1.0634x over previous
//
#include <hip/hip_runtime.h>
#include <cmath>

// Problem constants (fixed instantiation): x is [B, D] float32.
constexpr int B = 256;
constexpr int D = 512;
constexpr int ROW = D + D * D + D;          // 263168 floats per output row
constexpr int PAIR_ROWS_PER_BLOCK = 32;     // 32 rows x 128 float4-cols per block
constexpr int PAIR_BLOCKS = D / PAIR_ROWS_PER_BLOCK;  // 16
constexpr int BLOCKS_PER_BATCH = PAIR_BLOCKS + 1;     // +1 for sin+identity

// Best-measured structure (255.3 us total; kernel-delta ~93 us). Three
// structurally disjoint write patterns (this, nt-stores, device-linear
// window) all land within +-10% -> the limiter is external to the kernel
// (poison-fill L3 drain contention), so keep the simplest/best variant.
__global__ __launch_bounds__(256)
void basis_expansion_kernel(const float* __restrict__ x, float* __restrict__ out) {
    const int bid  = blockIdx.x;
    const int b    = bid / BLOCKS_PER_BATCH;
    const int part = bid % BLOCKS_PER_BATCH;
    const int t    = threadIdx.x;

    const float* xrow = x + b * D;
    float* orow = out + (size_t)b * ROW;

    __shared__ float sx[D];
    sx[t]       = xrow[t];
    sx[t + 256] = xrow[t + 256];
    __syncthreads();

    // Every thread owns one fixed float4 of the x row (column direction).
    const int col4 = t & 127;                 // 128 float4s cover D=512
    const float4 v = reinterpret_cast<const float4*>(sx)[col4];

    if (part == PAIR_BLOCKS) {
        // sin section (threads 0..127) + identity section (threads 128..255)
        if (t < 128) {
            float4 s;
            s.x = sinf(v.x); s.y = sinf(v.y); s.z = sinf(v.z); s.w = sinf(v.w);
            reinterpret_cast<float4*>(orow)[col4] = s;
        } else {
            reinterpret_cast<float4*>(orow + D + D * D)[col4] = v;
        }
        return;
    }

    // Pair section: out[b, D + i*D + j] = x[b,i] * x[b,j]
    // This block covers rows [part*32, part*32+32). Per iteration m, threads
    // 0..127 handle row 2m (cols 0..511 as float4), threads 128..255 row 2m+1.
    const int row0 = part * PAIR_ROWS_PER_BLOCK + (t >> 7);
    float4* pbase = reinterpret_cast<float4*>(orow + D);  // 16B aligned (512 % 4 == 0)

#pragma unroll
    for (int m = 0; m < PAIR_ROWS_PER_BLOCK / 2; ++m) {
        const int row = row0 + 2 * m;
        const float a = sx[row];              // LDS broadcast (conflict-free)
        float4 w;
        w.x = a * v.x; w.y = a * v.y; w.z = a * v.z; w.w = a * v.w;
        pbase[row * 128 + col4] = w;          // global_store_dwordx4, coalesced
    }
}

extern "C" void kernel_launch(void* const* d_in, const int* in_sizes, int n_in,
                              void* d_out, int out_size, void* d_ws, size_t ws_size,
                              hipStream_t stream) {
    const float* x = (const float*)d_in[0];
    float* out = (float*)d_out;
    dim3 grid(B * BLOCKS_PER_BATCH);
    dim3 block(256);
    basis_expansion_kernel<<<grid, block, 0, stream>>>(x, out);
}